// Round 6
// baseline (348.815 us; speedup 1.0000x reference)
//
#include <hip/hip_runtime.h>
#include <hip/hip_cooperative_groups.h>

namespace cg = cooperative_groups;

#define C_IN  128
#define C_RES 64
#define D     512
#define DD    (D * D)          // 262144 floats per c-slice
#define U4    (DD / 4)         // 65536 float4 units per (o,i) matrix

__device__ inline void acc4(float4& a, const float4& w) {
    a.x += w.x; a.y += w.y; a.z += w.z; a.w += w.w;
}

// 8 loads issued back-to-back (explicit memory-level parallelism).
__device__ inline void sum8(float4& a, const float4* __restrict__ p, int stride) {
    float4 r0 = p[0 * (size_t)stride];
    float4 r1 = p[1 * (size_t)stride];
    float4 r2 = p[2 * (size_t)stride];
    float4 r3 = p[3 * (size_t)stride];
    float4 r4 = p[4 * (size_t)stride];
    float4 r5 = p[5 * (size_t)stride];
    float4 r6 = p[6 * (size_t)stride];
    float4 r7 = p[7 * (size_t)stride];
    acc4(a, r0); acc4(a, r1); acc4(a, r2); acc4(a, r3);
    acc4(a, r4); acc4(a, r5); acc4(a, r6); acc4(a, r7);
}

// ---------------------------------------------------------------------------
// K1 (regular launch, 1024 blocks x 256): 4-way partial column sums of W1,W2
// + zero diff1|diff2. Thread (u = gtid&65535, p = gtid>>16):
//   P1[p][u] = sum_{c in [32p,32p+32)} W1[c] float4-chunk u    (32 loads)
//   P2[p][u] = sum_{c in [16p,16p+16)} W2[c] float4-chunk u    (16 loads)
// Proven near-BW-bound in R5 (the +34MB W2 fix cost only ~5.5us).
// ---------------------------------------------------------------------------
__global__ void __launch_bounds__(256, 4)
sum_kernel(const float* __restrict__ W1, const float* __restrict__ W2,
           float* __restrict__ P1, float* __restrict__ P2,
           float* __restrict__ diff_zero) {
    const int gtid = blockIdx.x * 256 + threadIdx.x;   // 0 .. 262143
    const int u = gtid & (U4 - 1);
    const int p = gtid >> 16;                          // 0..3

    const float4* w1p = (const float4*)W1 + (size_t)(32 * p) * U4 + u;
    float4 a1 = make_float4(0.f, 0.f, 0.f, 0.f);
    sum8(a1, w1p + (size_t)0  * U4, U4);
    sum8(a1, w1p + (size_t)8  * U4, U4);
    sum8(a1, w1p + (size_t)16 * U4, U4);
    sum8(a1, w1p + (size_t)24 * U4, U4);
    ((float4*)P1)[p * U4 + u] = a1;

    const float4* w2p = (const float4*)W2 + (size_t)(16 * p) * U4 + u;
    float4 a2 = make_float4(0.f, 0.f, 0.f, 0.f);
    sum8(a2, w2p + (size_t)0 * U4, U4);
    sum8(a2, w2p + (size_t)8 * U4, U4);
    ((float4*)P2)[p * U4 + u] = a2;

    if (gtid < (C_IN + C_RES) * D)                     // 98304: diff1|diff2
        diff_zero[gtid] = 0.f;
}

// ---------------------------------------------------------------------------
// K2 (cooperative, 256 blocks x 256 — grid <= CU count so co-residency holds):
//  Phase A: blocks 0..127 stage-1 / 128..255 stage-2, 4 columns each:
//           argmax_o of 4-partial sum (first-index tie-break), then
//           stage-1 scatter into diff1 / stage-2 gather w2v (+node2).
//  Phase B: blocks 0..127: x2 = relu(conv1+bc1); scatter into diff2.
//  Phase C: all 256 blocks: out = relu(x) + conv2 + bc2.
// grid.sync() = device-scope fence + barrier -> cross-XCD visibility of the
// diff1/diff2 atomics between phases.
// ---------------------------------------------------------------------------
__global__ void __launch_bounds__(256)
tail_kernel(const float* __restrict__ P1,  const float* __restrict__ P2,
            const float* __restrict__ W1,  const float* __restrict__ W2,
            const float* __restrict__ Wc1, const float* __restrict__ bc1,
            const float* __restrict__ Wc2, const float* __restrict__ bc2,
            const float* __restrict__ x,
            float* __restrict__ diff1,           // diff2 = diff1 + C_IN*D
            float* __restrict__ w2v, int* __restrict__ node2,
            float* __restrict__ out) {
    cg::grid_group grid = cg::this_grid();
    const int tid = threadIdx.x;
    const int bid = blockIdx.x;

    __shared__ float lv[256];
    __shared__ int   li[256];
    __shared__ int   node_s[4];
    __shared__ float wc[C_IN];

    float* __restrict__ diff2 = diff1 + C_IN * D;

    // ---------------- Phase A: argmax + scatter1 / gather2 -----------------
    {
        const bool st1 = bid < 128;
        const int  i0  = (st1 ? bid : bid - 128) * 4;
        const float* __restrict__ P = st1 ? P1 : P2;   // 4 planes of DD floats

        const int il = tid & 3;                        // column 0..3
        const int ol = tid >> 2;                       // 0..63
        float best = -__builtin_inff();
        int   bidx = D;
        for (int k = 0; k < 8; ++k) {
            int o = ol + (k << 6);                     // ascending per thread
            int base = o * D + i0 + il;
            float v = P[base] + P[DD + base] + P[2 * DD + base] + P[3 * DD + base];
            if (v > best) { best = v; bidx = o; }      // strict >: first wins
        }
        lv[tid] = best; li[tid] = bidx;
        __syncthreads();
        for (int s = 128; s >= 4; s >>= 1) {
            if (tid < s) {
                float v2 = lv[tid + s]; int i2 = li[tid + s];
                if (v2 > lv[tid] || (v2 == lv[tid] && i2 < li[tid])) {
                    lv[tid] = v2; li[tid] = i2;
                }
            }
            __syncthreads();
        }
        if (tid < 4) {
            node_s[tid] = li[tid];
            if (!st1) node2[i0 + tid] = li[tid];
        }
        __syncthreads();

        if (st1) {
            // 128 c x 4 i = 512 ops, 2 rounds
            for (int idx = tid; idx < C_IN * 4; idx += 256) {
                int ii = idx & 3;
                int c  = idx >> 2;
                int i  = i0 + ii;
                int n  = node_s[ii];
                float xv = fmaxf(x[c * D + i], 0.f);
                float w  = W1[(size_t)c * DD + (size_t)n * D + i];
                atomicAdd(&diff1[c * D + n], w * xv);
            }
        } else {
            // 64 c x 4 i = 256 ops, 1 round
            int ii = tid & 3;
            int c  = tid >> 2;
            if (c < C_RES) {
                int i = i0 + ii;
                int n = node_s[ii];
                w2v[c * D + i] = W2[(size_t)c * DD + (size_t)n * D + i];
            }
        }
    }

    grid.sync();

    // ---------------- Phase B: conv1 (+bias, relu) + scatter2 --------------
    if (bid < 128) {
        const int c = bid >> 1;                        // 0..63
        const int i = ((bid & 1) << 8) + tid;
        if (tid < C_IN) wc[tid] = Wc1[c * C_IN + tid];
        __syncthreads();

        float acc = bc1[c];
#pragma unroll 8
        for (int cc = 0; cc < C_IN; ++cc)
            acc += wc[cc] * diff1[cc * D + i];
        float x2 = fmaxf(acc, 0.f);
        int n = node2[i];
        atomicAdd(&diff2[c * D + n], w2v[c * D + i] * x2);
    }

    grid.sync();

    // ---------------- Phase C: conv2 + bias + residual relu(x) -------------
    {
        const int o = bid >> 1;                        // 0..127
        const int d = ((bid & 1) << 8) + tid;
        __syncthreads();                               // wc reuse safety
        if (tid < C_RES) wc[tid] = Wc2[o * C_RES + tid];
        __syncthreads();

        float acc = bc2[o];
#pragma unroll 8
        for (int c = 0; c < C_RES; ++c)
            acc += wc[c] * diff2[c * D + d];
        out[o * D + d] = acc + fmaxf(x[o * D + d], 0.f);
    }
}

extern "C" void kernel_launch(void* const* d_in, const int* in_sizes, int n_in,
                              void* d_out, int out_size, void* d_ws, size_t ws_size,
                              hipStream_t stream) {
    const float* x   = (const float*)d_in[0];   // (1, 128, 512)
    const float* W1  = (const float*)d_in[1];   // (128, 512, 512)
    const float* Wc1 = (const float*)d_in[2];   // (64, 128)
    const float* bc1 = (const float*)d_in[3];   // (64,)
    const float* W2  = (const float*)d_in[4];   // (64, 512, 512)
    const float* Wc2 = (const float*)d_in[5];   // (128, 64)
    const float* bc2 = (const float*)d_in[6];   // (128,)
    float* out = (float*)d_out;                 // (1, 128, 512) fp32

    // Workspace carve-up (floats)
    float* ws    = (float*)d_ws;
    float* P1    = ws;                          // 4 planes * 262144 = 4 MB
    float* P2    = P1 + 4 * DD;                 // 4 MB
    float* diff1 = P2 + 4 * DD;                 // 65536 (+ diff2 32768 contiguous)
    float* w2v   = diff1 + (C_IN + C_RES) * D;  // 32768
    int*   node2 = (int*)(w2v + C_RES * D);     // 512

    // K1: stream W1+W2 (201 MB — the HBM floor); zero diff buffers.
    sum_kernel<<<1024, 256, 0, stream>>>(W1, W2, P1, P2, diff1);

    // K2: cooperative tail — argmax/scatter/gather, conv1+scatter2, final.
    void* args[] = {
        (void*)&P1, (void*)&P2, (void*)&W1, (void*)&W2, (void*)&Wc1,
        (void*)&bc1, (void*)&Wc2, (void*)&bc2, (void*)&x, (void*)&diff1,
        (void*)&w2v, (void*)&node2, (void*)&out,
    };
    hipLaunchCooperativeKernel((void*)tail_kernel, dim3(256), dim3(256),
                               args, 0, stream);
}

// Round 7
// 263.006 us; speedup vs baseline: 1.3263x; 1.3263x over previous
//
#include <hip/hip_runtime.h>

#define C_IN  128
#define C_RES 64
#define D     512
#define DD    (D * D)          // 262144 floats per c-slice
#define U4    (DD / 4)         // 65536 float4 units per (o,i) matrix

__device__ inline void acc4(float4& a, const float4& w) {
    a.x += w.x; a.y += w.y; a.z += w.z; a.w += w.w;
}

// 8 loads issued back-to-back (explicit memory-level parallelism).
__device__ inline void sum8(float4& a, const float4* __restrict__ p, size_t stride) {
    float4 r0 = p[0 * stride];
    float4 r1 = p[1 * stride];
    float4 r2 = p[2 * stride];
    float4 r3 = p[3 * stride];
    float4 r4 = p[4 * stride];
    float4 r5 = p[5 * stride];
    float4 r6 = p[6 * stride];
    float4 r7 = p[7 * stride];
    acc4(a, r0); acc4(a, r1); acc4(a, r2); acc4(a, r3);
    acc4(a, r4); acc4(a, r5); acc4(a, r6); acc4(a, r7);
}

// ---------------------------------------------------------------------------
// K1: single-pass full column sums (no partial planes).
// 1024 blocks x 256. Block b<512: W1 row o=b; else W2 row o=b-512.
// Thread: i4 = tid&127 (its float4 column chunk), ch = tid>>7 (c parity).
// Sums c = ch, ch+2, ... (64 steps W1 / 32 steps W2) in 8-deep MLP batches;
// halves combined via LDS; coalesced 2KB row write of final S.
// Also zeroes diff1|diff2 (first 384 blocks' threads).
// ---------------------------------------------------------------------------
__global__ void __launch_bounds__(256, 4)
sum_kernel(const float* __restrict__ W1, const float* __restrict__ W2,
           float* __restrict__ S1, float* __restrict__ S2,
           float* __restrict__ diff_zero) {
    const int tid = threadIdx.x;
    const int bid = blockIdx.x;
    const int i4  = tid & 127;
    const int ch  = tid >> 7;                     // c parity 0/1
    const size_t st = 2 * (size_t)U4;             // stride between same-parity slices

    __shared__ float4 sh[128];

    if (bid < 512) {                              // ---- W1 row o = bid ----
        const int o = bid;
        const float4* p = (const float4*)W1 + (size_t)ch * U4
                        + (size_t)o * (D / 4) + i4;
        float4 a = make_float4(0.f, 0.f, 0.f, 0.f);
        sum8(a, p + 0  * st, st);                 // c-steps 0..7   (parity ch)
        sum8(a, p + 8  * st, st);
        sum8(a, p + 16 * st, st);
        sum8(a, p + 24 * st, st);
        sum8(a, p + 32 * st, st);
        sum8(a, p + 40 * st, st);
        sum8(a, p + 48 * st, st);
        sum8(a, p + 56 * st, st);                 // 64 steps = all c of parity ch
        if (ch) sh[i4] = a;
        __syncthreads();
        if (!ch) {
            acc4(a, sh[i4]);
            ((float4*)S1)[o * (D / 4) + i4] = a;
        }
    } else {                                      // ---- W2 row o = bid-512 ----
        const int o = bid - 512;
        const float4* p = (const float4*)W2 + (size_t)ch * U4
                        + (size_t)o * (D / 4) + i4;
        float4 a = make_float4(0.f, 0.f, 0.f, 0.f);
        sum8(a, p + 0  * st, st);
        sum8(a, p + 8  * st, st);
        sum8(a, p + 16 * st, st);
        sum8(a, p + 24 * st, st);                 // 32 steps = all c of parity ch
        if (ch) sh[i4] = a;
        __syncthreads();
        if (!ch) {
            acc4(a, sh[i4]);
            ((float4*)S2)[o * (D / 4) + i4] = a;
        }
    }

    const int gtid = bid * 256 + tid;
    if (gtid < (C_IN + C_RES) * D)                // 98304: diff1|diff2
        diff_zero[gtid] = 0.f;
}

// ---------------------------------------------------------------------------
// K2: 128 blocks x 256. Blocks 0..63 (stage 1) / 64..127 (stage 2), 8 cols
// each: argmax_o S (first-index tie-break), then stage-1 scatter into diff1 /
// stage-2 gather into w2v (+node2).
// ---------------------------------------------------------------------------
__global__ void argmax_scatter_kernel(const float* __restrict__ S1,
                                      const float* __restrict__ S2,
                                      const float* __restrict__ W1,
                                      const float* __restrict__ W2,
                                      const float* __restrict__ x,
                                      float* __restrict__ diff1,
                                      float* __restrict__ w2v,
                                      int* __restrict__ node2) {
    __shared__ float lv[256];
    __shared__ int   li[256];
    __shared__ int   node_s[8];

    const int  tid = threadIdx.x;
    const int  bid = blockIdx.x;
    const bool st1 = bid < 64;
    const int  i0  = (st1 ? bid : bid - 64) * 8;
    const float* __restrict__ S = st1 ? S1 : S2;

    const int il = tid & 7;                            // column 0..7
    const int ol = tid >> 3;                           // 0..31
    float best = -__builtin_inff();
    int   bidx = D;
    for (int k = 0; k < 16; ++k) {
        int o = ol + (k << 5);                         // ascending per thread
        float v = S[o * D + i0 + il];
        if (v > best) { best = v; bidx = o; }          // strict >: first wins
    }
    lv[tid] = best; li[tid] = bidx;
    __syncthreads();
    for (int s = 128; s >= 8; s >>= 1) {
        if (tid < s) {
            float v2 = lv[tid + s]; int i2 = li[tid + s];
            if (v2 > lv[tid] || (v2 == lv[tid] && i2 < li[tid])) {
                lv[tid] = v2; li[tid] = i2;
            }
        }
        __syncthreads();
    }
    if (tid < 8) {
        node_s[tid] = li[tid];
        if (!st1) node2[i0 + tid] = li[tid];
    }
    __syncthreads();

    if (st1) {
        for (int idx = tid; idx < C_IN * 8; idx += 256) {
            int ii = idx & 7;
            int c  = idx >> 3;
            int i  = i0 + ii;
            int n  = node_s[ii];
            float xv = fmaxf(x[c * D + i], 0.f);
            float w  = W1[(size_t)c * DD + (size_t)n * D + i];
            atomicAdd(&diff1[c * D + n], w * xv);
        }
    } else {
        for (int idx = tid; idx < C_RES * 8; idx += 256) {
            int ii = idx & 7;
            int c  = idx >> 3;
            int i  = i0 + ii;
            int n  = node_s[ii];
            w2v[c * D + i] = W2[(size_t)c * DD + (size_t)n * D + i];
        }
    }
}

// ---------------------------------------------------------------------------
// K3: x2 = relu(bc1[c] + sum_cc Wc1[c,cc]*diff1[cc,i]);
//     diff2[c, node2[i]] += w2v[c,i] * x2.   128 blocks x 256.
// ---------------------------------------------------------------------------
__global__ void conv1_scatter2_kernel(const float* __restrict__ Wc1,
                                      const float* __restrict__ bc1,
                                      const float* __restrict__ diff1,
                                      const float* __restrict__ w2v,
                                      const int* __restrict__ node2,
                                      float* __restrict__ diff2) {
    __shared__ float wc[C_IN];
    const int c = blockIdx.x >> 1;                     // 0..63
    const int i = ((blockIdx.x & 1) << 8) + threadIdx.x;
    if (threadIdx.x < C_IN) wc[threadIdx.x] = Wc1[c * C_IN + threadIdx.x];
    __syncthreads();

    float acc = bc1[c];
#pragma unroll 8
    for (int cc = 0; cc < C_IN; ++cc)
        acc += wc[cc] * diff1[cc * D + i];
    float x2 = fmaxf(acc, 0.f);
    int n = node2[i];
    atomicAdd(&diff2[c * D + n], w2v[c * D + i] * x2);
}

// ---------------------------------------------------------------------------
// K4: out[o,d] = relu(x[o,d]) + bc2[o] + sum_c Wc2[o,c]*diff2[c,d].
// 256 blocks x 256.
// ---------------------------------------------------------------------------
__global__ void final_kernel(const float* __restrict__ Wc2,
                             const float* __restrict__ bc2,
                             const float* __restrict__ diff2,
                             const float* __restrict__ x,
                             float* __restrict__ out) {
    __shared__ float wc[C_RES];
    const int o = blockIdx.x >> 1;                     // 0..127
    const int d = ((blockIdx.x & 1) << 8) + threadIdx.x;
    if (threadIdx.x < C_RES) wc[threadIdx.x] = Wc2[o * C_RES + threadIdx.x];
    __syncthreads();

    float acc = bc2[o];
#pragma unroll 8
    for (int c = 0; c < C_RES; ++c)
        acc += wc[c] * diff2[c * D + d];
    out[o * D + d] = acc + fmaxf(x[o * D + d], 0.f);
}

extern "C" void kernel_launch(void* const* d_in, const int* in_sizes, int n_in,
                              void* d_out, int out_size, void* d_ws, size_t ws_size,
                              hipStream_t stream) {
    const float* x   = (const float*)d_in[0];   // (1, 128, 512)
    const float* W1  = (const float*)d_in[1];   // (128, 512, 512)
    const float* Wc1 = (const float*)d_in[2];   // (64, 128)
    const float* bc1 = (const float*)d_in[3];   // (64,)
    const float* W2  = (const float*)d_in[4];   // (64, 512, 512)
    const float* Wc2 = (const float*)d_in[5];   // (128, 64)
    const float* bc2 = (const float*)d_in[6];   // (128,)
    float* out = (float*)d_out;                 // (1, 128, 512) fp32

    // Workspace carve-up (floats)
    float* ws    = (float*)d_ws;
    float* S1    = ws;                          // 262144 (1 MB)
    float* S2    = S1 + DD;                     // 262144 (1 MB)
    float* diff1 = S2 + DD;                     // 65536 (+ diff2 32768 contiguous)
    float* diff2 = diff1 + C_IN * D;
    float* w2v   = diff2 + C_RES * D;           // 32768
    int*   node2 = (int*)(w2v + C_RES * D);     // 512

    // K1: stream W1+W2 (201 MB — the HBM floor), single-pass sums; zero diffs.
    sum_kernel<<<1024, 256, 0, stream>>>(W1, W2, S1, S2, diff1);
    // K2: argmax + stage-1 scatter + stage-2 gather.
    argmax_scatter_kernel<<<128, 256, 0, stream>>>(S1, S2, W1, W2, x,
                                                   diff1, w2v, node2);
    // K3: stage-1 1x1 conv (+bias, relu) fused with stage-2 scatter.
    conv1_scatter2_kernel<<<128, 256, 0, stream>>>(Wc1, bc1, diff1, w2v,
                                                   node2, diff2);
    // K4: stage-2 1x1 conv + bias + residual relu(x).
    final_kernel<<<256, 256, 0, stream>>>(Wc2, bc2, diff2, x, out);
}